// Round 8
// baseline (353.012 us; speedup 1.0000x reference)
//
#include <hip/hip_runtime.h>
#include <math.h>

#define DEV __device__ __forceinline__

typedef __attribute__((ext_vector_type(8))) __bf16 bf16x8;
typedef __attribute__((ext_vector_type(4))) float f32x4;

DEV __bf16 to_bf16(float v) { return (__bf16)v; }
DEV __bf16 to_bf16(__bf16 v) { return v; }

// ============ prep (single dispatch): all weights fp32->bf16 (K-padded); fold BN ============
__global__ void prep_all(
    const float* __restrict__ c1w, const float* __restrict__ c1b,
    const float* __restrict__ g1, const float* __restrict__ b1,
    const float* __restrict__ m1, const float* __restrict__ v1,
    const float* __restrict__ c2w, const float* __restrict__ c2b,
    const float* __restrict__ g2, const float* __restrict__ b2,
    const float* __restrict__ m2, const float* __restrict__ v2,
    const float* __restrict__ c3w, const float* __restrict__ c3b,
    const float* __restrict__ g3, const float* __restrict__ b3,
    const float* __restrict__ m3, const float* __restrict__ v3,
    __bf16* __restrict__ wb1, __bf16* __restrict__ wb2, __bf16* __restrict__ wb3,
    float* __restrict__ sc1, float* __restrict__ sh1,
    float* __restrict__ sc2, float* __restrict__ sh2,
    float* __restrict__ sc3, float* __restrict__ sh3)
{
    int gid = blockIdx.x * 256 + threadIdx.x;
    int gs = gridDim.x * 256;
    for (int e = gid; e < 32 * 160; e += gs) {
        int oc = e / 160, k = e % 160;
        wb1[e] = (k < 147) ? (__bf16)c1w[oc * 147 + k] : (__bf16)0.f;
    }
    for (int e = gid; e < 64 * 288; e += gs) wb2[e] = (__bf16)c2w[e];
    for (int e = gid; e < 128 * 576; e += gs) wb3[e] = (__bf16)c3w[e];
    if (gid < 32) {
        float s = g1[gid] * rsqrtf(v1[gid] + 1e-5f);
        sc1[gid] = s; sh1[gid] = (c1b[gid] - m1[gid]) * s + b1[gid];
    } else if (gid < 96) {
        int i = gid - 32;
        float s = g2[i] * rsqrtf(v2[i] + 1e-5f);
        sc2[i] = s; sh2[i] = (c2b[i] - m2[i]) * s + b2[i];
    } else if (gid < 224) {
        int i = gid - 96;
        float s = g3[i] * rsqrtf(v3[i] + 1e-5f);
        sc3[i] = s; sh3[i] = (c3b[i] - m3[i]) * s + b3[i];
    }
}

// ============ bf16 MFMA implicit-GEMM conv, software-pipelined ============
// D[oc][s] = sum_k W[oc][k] * im2col[k][s]. Block: 32 oc x 128 spatial, BK=32.
// KOFF template constant -> fully-unrolled K loop makes every kg compile-time.
// Pipeline: regs hold chunk ci+1 while MFMA consumes chunk ci from LDS buf[ci&1];
// gathers for chunk ci+2 issue right after the buf[(ci+1)&1] write -> one full
// iteration of latency hiding per load batch. ONE barrier per chunk.
template<typename INT, typename OUTT,
         int IC, int KS, int S, int P, int IH, int IW, int OH, int OW, int OC,
         int KTP, int KOFF, int KCH, bool EPI>
__global__ __launch_bounds__(256, 4) void conv_mfma_kernel(
    const INT* __restrict__ x,        // (N,IC,IH,IW)
    const __bf16* __restrict__ wb,    // (OC,KTP) bf16, zero-padded
    const float* __restrict__ scale,  // (OC)
    const float* __restrict__ shift,  // (OC)
    OUTT* __restrict__ out)           // (N,OC,OH,OW)
{
    constexpr int KT = IC * KS * KS;
    constexpr int KITER = KCH / 32;
    static_assert(KCH % 32 == 0, "KCH");
    constexpr int OHW = OH * OW;
    constexpr int IHW = IH * IW;
    constexpr int LDR = 40;   // halfs per row (32 data + 8 pad); rows 16B-aligned

    __shared__ __attribute__((aligned(16))) __bf16 Is[2][128 * LDR]; // [spatial][k]
    __shared__ __attribute__((aligned(16))) __bf16 Ws[2][32 * LDR];  // [oc][k]

    const int tid = threadIdx.x;
    const int sb0 = blockIdx.x * 128;
    const int oc0 = blockIdx.y * 32;

    // --- Is staging coords: row sm, k in [kpb*16, kpb*16+16) (kpb wave-uniform) ---
    const int sm = tid & 127;
    const int kpb = tid >> 7;
    int a_n, a_ih0, a_iw0;
    {
        int m = sb0 + sm;
        a_n = m / OHW;
        int rem = m % OHW;
        a_ih0 = (rem / OW) * S - P;
        a_iw0 = (rem % OW) * S - P;
    }
    unsigned ihok = 0, iwok = 0;
    #pragma unroll
    for (int t = 0; t < KS; ++t) {
        ihok |= (unsigned)(((a_ih0 + t) >= 0) && ((a_ih0 + t) < IH)) << t;
        iwok |= (unsigned)(((a_iw0 + t) >= 0) && ((a_iw0 + t) < IW)) << t;
    }
    const INT* xp = x + (size_t)a_n * IC * IHW + (ptrdiff_t)a_ih0 * IW + a_iw0;

    auto gather1 = [&](int kg) -> __bf16 {
        if (kg >= KT) return (__bf16)0.f;          // compile-time after unroll
        const int ic = kg / (KS * KS);
        const int r  = kg % (KS * KS);
        const int kh = r / KS, kw = r % KS;
        bool ok = ((ihok >> kh) & 1u) && ((iwok >> kw) & 1u);
        __bf16 v = (__bf16)0.f;
        if (ok) v = to_bf16(xp[ic * IHW + kh * IW + kw]);
        return v;
    };
    // --- Ws staging coords (threads 0..127): oc row, 8-k octet j ---
    const int w_oc = tid >> 2;      // 0..31 for tid<128
    const int w_j  = tid & 3;

    auto gatherChunk = [&](int ci, bf16x8& v0, bf16x8& v1, bf16x8& wv) {
        const int k0 = KOFF + ci * 32;
        if (kpb == 0) {
            #pragma unroll
            for (int j = 0; j < 8; ++j) v0[j] = gather1(k0 + j);
            #pragma unroll
            for (int j = 0; j < 8; ++j) v1[j] = gather1(k0 + 8 + j);
        } else {
            #pragma unroll
            for (int j = 0; j < 8; ++j) v0[j] = gather1(k0 + 16 + j);
            #pragma unroll
            for (int j = 0; j < 8; ++j) v1[j] = gather1(k0 + 24 + j);
        }
        wv = (bf16x8){};
        if (tid < 128)
            wv = *(const bf16x8*)&wb[(size_t)(oc0 + w_oc) * KTP + k0 + w_j * 8];
    };
    auto stageChunk = [&](int buf, const bf16x8& v0, const bf16x8& v1,
                          const bf16x8& wv) {
        *(bf16x8*)&Is[buf][sm * LDR + kpb * 16]     = v0;
        *(bf16x8*)&Is[buf][sm * LDR + kpb * 16 + 8] = v1;
        if (tid < 128) *(bf16x8*)&Ws[buf][w_oc * LDR + w_j * 8] = wv;
    };

    const int wave = tid >> 6, lane = tid & 63;
    const int quad = lane >> 4, l16 = lane & 15;

    f32x4 acc[2][2] = {};

    // ---- pipeline prologue ----
    bf16x8 g0, g1v, gw;
    gatherChunk(0, g0, g1v, gw);
    stageChunk(0, g0, g1v, gw);
    if (KITER > 1) gatherChunk(1, g0, g1v, gw);
    __syncthreads();

    #pragma unroll
    for (int ci = 0; ci < KITER; ++ci) {
        // ---- MFMA on buf ci&1 ----
        bf16x8 afr[2], bfr[2];
        #pragma unroll
        for (int mt = 0; mt < 2; ++mt)
            afr[mt] = *(const bf16x8*)&Ws[ci & 1][(mt * 16 + l16) * LDR + quad * 8];
        #pragma unroll
        for (int nt = 0; nt < 2; ++nt)
            bfr[nt] = *(const bf16x8*)&Is[ci & 1][(wave * 32 + nt * 16 + l16) * LDR + quad * 8];
        #pragma unroll
        for (int mt = 0; mt < 2; ++mt)
            #pragma unroll
            for (int nt = 0; nt < 2; ++nt)
                acc[mt][nt] = __builtin_amdgcn_mfma_f32_16x16x32_bf16(
                    afr[mt], bfr[nt], acc[mt][nt], 0, 0, 0);

        if (ci + 1 < KITER) {
            stageChunk((ci + 1) & 1, g0, g1v, gw);     // vmcnt waits for chunk ci+1
            if (ci + 2 < KITER) gatherChunk(ci + 2, g0, g1v, gw);  // issue only
            __syncthreads();
        }
    }

    // ---- epilogue: D row = oc (quad*4+r), col = spatial (l16) ----
    #pragma unroll
    for (int mt = 0; mt < 2; ++mt) {
        #pragma unroll
        for (int r = 0; r < 4; ++r) {
            int oc = oc0 + mt * 16 + quad * 4 + r;
            float scl = EPI ? scale[oc] : 0.f;
            float shf = EPI ? shift[oc] : 0.f;
            #pragma unroll
            for (int nt = 0; nt < 2; ++nt) {
                int sg = sb0 + wave * 32 + nt * 16 + l16;
                int n = sg / OHW, s = sg % OHW;
                float v = acc[mt][nt][r];
                if (EPI) {
                    v = fmaf(v, scl, shf);
                    v = v > 0.f ? v : 0.f;
                }
                out[((size_t)n * OC + oc) * OHW + s] = (OUTT)v;
            }
        }
    }
}

// ============ pool: sum split-K partials + BN3 + ReLU + 7x7 avg ============
// one thread per pooled output: (N,512) -> 256 blocks x 256 threads for N=128
__global__ __launch_bounds__(256) void pool_bn_kernel(
    const float* __restrict__ p3a, const float* __restrict__ p3b,
    const float* __restrict__ sc3, const float* __restrict__ sh3,
    float* __restrict__ f)               // (N,512)
{
    int idx = blockIdx.x * 256 + threadIdx.x;
    int b = idx >> 9, p = idx & 511;
    int c = p >> 2, i = (p >> 1) & 1, j = p & 1;
    size_t base = ((size_t)b * 128 + c) * 196 + (i * 7) * 14 + j * 7;
    float scl = sc3[c], shf = sh3[c];
    float s = 0.f;
    #pragma unroll
    for (int u = 0; u < 7; ++u)
        #pragma unroll
        for (int v = 0; v < 7; ++v) {
            size_t k = base + u * 14 + v;
            float val = fmaf(p3a[k] + p3b[k], scl, shf);
            s += val > 0.f ? val : 0.f;
        }
    f[idx] = s * (1.f / 49.f);
}

// ============ quantum gate helpers ============
DEV void gate_ry(float* re, float* im, int q, float th) {
    float c = cosf(th * 0.5f), s = sinf(th * 0.5f);
    int mask = 8 >> q;
    for (int i = 0; i < 16; ++i) {
        if (i & mask) continue;
        int j = i | mask;
        float r0 = re[i], i0 = im[i], r1 = re[j], i1 = im[j];
        re[i] = c * r0 - s * r1;  im[i] = c * i0 - s * i1;
        re[j] = s * r0 + c * r1;  im[j] = s * i0 + c * i1;
    }
}
DEV void gate_rx(float* re, float* im, int q, float th) {
    float c = cosf(th * 0.5f), s = sinf(th * 0.5f);
    int mask = 8 >> q;
    for (int i = 0; i < 16; ++i) {
        if (i & mask) continue;
        int j = i | mask;
        float r0 = re[i], i0 = im[i], r1 = re[j], i1 = im[j];
        re[i] = c * r0 + s * i1;  im[i] = c * i0 - s * r1;
        re[j] = s * i0 + c * r1;  im[j] = -s * r0 + c * i1;
    }
}
DEV void gate_rz(float* re, float* im, int q, float th) {
    float c = cosf(th * 0.5f), s = sinf(th * 0.5f);
    int mask = 8 >> q;
    for (int i = 0; i < 16; ++i) {
        float sg = (i & mask) ? s : -s;
        float r = re[i], m = im[i];
        re[i] = c * r - sg * m;
        im[i] = c * m + sg * r;
    }
}
DEV void gate_cnot(float* re, float* im, int c, int t) {
    int cm = 8 >> c, tm = 8 >> t;
    for (int i = 0; i < 16; ++i) {
        if ((i & cm) && !(i & tm)) {
            int j = i | tm;
            float r = re[i]; re[i] = re[j]; re[j] = r;
            float m = im[i]; im[i] = im[j]; im[j] = m;
        }
    }
}

// ============ head: linear/tanh -> circuit -> MLP (reads pooled f) ============
__global__ __launch_bounds__(256) void head_kernel(
    const float* __restrict__ fpool,     // (N,512)
    const float* __restrict__ pre_w, const float* __restrict__ pre_b,
    const float* __restrict__ qw,
    const float* __restrict__ pw1, const float* __restrict__ pb1,
    const float* __restrict__ pw2, const float* __restrict__ pb2,
    float* __restrict__ out)             // (N,5)
{
    __shared__ float f[512];
    __shared__ float ang[4];
    __shared__ float sre[16], simg[16];
    __shared__ float zexp[4];
    __shared__ float h1[64];

    int b = blockIdx.x;
    int t = threadIdx.x;

    for (int p = t; p < 512; p += 256) f[p] = fpool[b * 512 + p];
    __syncthreads();

    int wv = t >> 6, lane = t & 63;
    float partial = 0.f;
    for (int d = lane; d < 512; d += 64)
        partial += f[d] * pre_w[wv * 512 + d];
    #pragma unroll
    for (int off = 32; off > 0; off >>= 1)
        partial += __shfl_down(partial, off, 64);
    if (lane == 0)
        ang[wv] = tanhf(partial + pre_b[wv]) * 3.14159265358979323846f;
    __syncthreads();

    if (t == 0) {
        for (int i = 0; i < 16; ++i) { sre[i] = 0.f; simg[i] = 0.f; }
        sre[0] = 1.f;
        for (int q = 0; q < 4; ++q) gate_ry(sre, simg, q, ang[q]);
        for (int l = 0; l < 2; ++l) {
            for (int q = 0; q < 4; ++q) {
                const float* qq = qw + (l * 4 + q) * 3;
                gate_rx(sre, simg, q, qq[0]);
                gate_ry(sre, simg, q, qq[1]);
                gate_rz(sre, simg, q, qq[2]);
            }
            gate_cnot(sre, simg, 0, 1);
            gate_cnot(sre, simg, 1, 2);
            gate_cnot(sre, simg, 2, 3);
            gate_cnot(sre, simg, 3, 0);
        }
        for (int q = 0; q < 4; ++q) {
            float z = 0.f;
            for (int i = 0; i < 16; ++i) {
                float p2 = sre[i] * sre[i] + simg[i] * simg[i];
                z += (((i >> (3 - q)) & 1) ? -p2 : p2);
            }
            zexp[q] = z;
        }
    }
    __syncthreads();

    if (t < 64) {
        float s = pb1[t];
        #pragma unroll
        for (int k = 0; k < 4; ++k) s += zexp[k] * pw1[t * 4 + k];
        h1[t] = s > 0.f ? s : 0.f;
    }
    __syncthreads();

    if (t < 5) {
        float s = pb2[t];
        for (int k = 0; k < 64; ++k) s += h1[k] * pw2[t * 64 + k];
        out[b * 5 + t] = s;
    }
}

extern "C" void kernel_launch(void* const* d_in, const int* in_sizes, int n_in,
                              void* d_out, int out_size, void* d_ws, size_t ws_size,
                              hipStream_t stream) {
    const float* x    = (const float*)d_in[0];
    const float* c1w  = (const float*)d_in[1];
    const float* c1b  = (const float*)d_in[2];
    const float* bn1g = (const float*)d_in[3];
    const float* bn1b = (const float*)d_in[4];
    const float* bn1m = (const float*)d_in[5];
    const float* bn1v = (const float*)d_in[6];
    const float* c2w  = (const float*)d_in[7];
    const float* c2b  = (const float*)d_in[8];
    const float* bn2g = (const float*)d_in[9];
    const float* bn2b = (const float*)d_in[10];
    const float* bn2m = (const float*)d_in[11];
    const float* bn2v = (const float*)d_in[12];
    const float* c3w  = (const float*)d_in[13];
    const float* c3bi = (const float*)d_in[14];
    const float* bn3g = (const float*)d_in[15];
    const float* bn3b = (const float*)d_in[16];
    const float* bn3m = (const float*)d_in[17];
    const float* bn3v = (const float*)d_in[18];
    const float* prw  = (const float*)d_in[19];
    const float* prb  = (const float*)d_in[20];
    const float* qw   = (const float*)d_in[21];
    const float* pw1  = (const float*)d_in[22];
    const float* pb1  = (const float*)d_in[23];
    const float* pw2  = (const float*)d_in[24];
    const float* pb2  = (const float*)d_in[25];

    const int N = in_sizes[0] / (3 * 224 * 224);   // 128

    // ---- workspace layout ----
    __bf16* c1o = (__bf16*)d_ws;                     // N*32*56*56 = 12,845,056 halfs
    __bf16* c2o = c1o + (size_t)N * 32 * 56 * 56;    // N*64*28*28 =  6,422,528 halfs
    __bf16* wb1 = c2o + (size_t)N * 64 * 28 * 28;    // 32*160  (16B-aligned)
    __bf16* wb2 = wb1 + 32 * 160;                    // 64*288
    __bf16* wb3 = wb2 + 64 * 288;                    // 128*576
    float* sc1 = (float*)(wb3 + 128 * 576);
    float* sh1 = sc1 + 32;
    float* sc2 = sh1 + 32;  float* sh2 = sc2 + 64;
    float* sc3 = sh2 + 64;  float* sh3 = sc3 + 128;
    float* fpool = sh3 + 128;                        // N*512 floats
    // conv3 split-K fp32 partials alias the (dead after conv2) c1o region:
    float* p3a = (float*)d_ws;
    float* p3b = p3a + (size_t)N * 128 * 14 * 14;

    prep_all<<<380, 256, 0, stream>>>(
        c1w, c1b, bn1g, bn1b, bn1m, bn1v,
        c2w, c2b, bn2g, bn2b, bn2m, bn2v,
        c3w, c3bi, bn3g, bn3b, bn3m, bn3v,
        wb1, wb2, wb3, sc1, sh1, sc2, sh2, sc3, sh3);

    // conv1: fp32 in -> bf16 out.  KTP=160, KOFF=0, KCH=160 (KT=147 zero-padded).
    conv_mfma_kernel<float, __bf16, 3, 7, 4, 3, 224, 224, 56, 56, 32, 160, 0, 160, true>
        <<<dim3(401408 / 128, 1), 256, 0, stream>>>(x, wb1, sc1, sh1, c1o);
    // conv2: bf16 in -> bf16 out.  KTP=288, full K.
    conv_mfma_kernel<__bf16, __bf16, 32, 3, 2, 1, 56, 56, 28, 28, 64, 288, 0, 288, true>
        <<<dim3(100352 / 128, 2), 256, 0, stream>>>(c1o, wb2, sc2, sh2, c2o);
    // conv3: bf16 in -> fp32 raw partials, split-K as two constexpr-offset launches.
    conv_mfma_kernel<__bf16, float, 64, 3, 2, 1, 28, 28, 14, 14, 128, 576, 0, 288, false>
        <<<dim3(25088 / 128, 4), 256, 0, stream>>>(c2o, wb3, sc3, sh3, p3a);
    conv_mfma_kernel<__bf16, float, 64, 3, 2, 1, 28, 28, 14, 14, 128, 576, 288, 288, false>
        <<<dim3(25088 / 128, 4), 256, 0, stream>>>(c2o, wb3, sc3, sh3, p3b);

    pool_bn_kernel<<<(N * 512) / 256, 256, 0, stream>>>(p3a, p3b, sc3, sh3, fpool);
    head_kernel<<<N, 256, 0, stream>>>(fpool, prw, prb, qw,
                                       pw1, pb1, pw2, pb2, (float*)d_out);
}

// Round 9
// 269.018 us; speedup vs baseline: 1.3122x; 1.3122x over previous
//
#include <hip/hip_runtime.h>
#include <math.h>

#define DEV __device__ __forceinline__

typedef __attribute__((ext_vector_type(8))) __bf16 bf16x8;
typedef __attribute__((ext_vector_type(4))) float f32x4;

// ============ prep: x fp32->bf16 copy; weights to row-padded bf16; BN fold ============
__global__ void prep_all(
    const float* __restrict__ x, long nx,
    const float* __restrict__ c1w, const float* __restrict__ c1b,
    const float* __restrict__ g1, const float* __restrict__ b1,
    const float* __restrict__ m1, const float* __restrict__ v1,
    const float* __restrict__ c2w, const float* __restrict__ c2b,
    const float* __restrict__ g2, const float* __restrict__ b2,
    const float* __restrict__ m2, const float* __restrict__ v2,
    const float* __restrict__ c3w, const float* __restrict__ c3b,
    const float* __restrict__ g3, const float* __restrict__ b3,
    const float* __restrict__ m3, const float* __restrict__ v3,
    __bf16* __restrict__ xpad,
    __bf16* __restrict__ wb1, __bf16* __restrict__ wb2, __bf16* __restrict__ wb3,
    float* __restrict__ sc1, float* __restrict__ sh1,
    float* __restrict__ sc2, float* __restrict__ sh2,
    float* __restrict__ sc3, float* __restrict__ sh3)
{
    long gid = (long)blockIdx.x * 256 + threadIdx.x;
    long gs = (long)gridDim.x * 256;
    for (long e = gid; e < nx; e += gs) xpad[e] = (__bf16)x[e];

    // wb1: [32][192], rows of 8 (7 real); rr = k/8 < 21 real
    for (long e = gid; e < 32 * 192; e += gs) {
        int oc = e / 192, k = e % 192, rr = k >> 3, kw = k & 7;
        wb1[e] = (rr < 21 && kw < 7) ? (__bf16)c1w[oc * 147 + rr * 7 + kw] : (__bf16)0.f;
    }
    // wb2: [64][384], rows of 4 (3 real)
    for (long e = gid; e < 64 * 384; e += gs) {
        int oc = e / 384, k = e % 384, rr = k >> 2, kw = k & 3;
        wb2[e] = (kw < 3) ? (__bf16)c2w[oc * 288 + rr * 3 + kw] : (__bf16)0.f;
    }
    // wb3: [128][768], rows of 4 (3 real)
    for (long e = gid; e < 128 * 768; e += gs) {
        int oc = e / 768, k = e % 768, rr = k >> 2, kw = k & 3;
        wb3[e] = (kw < 3) ? (__bf16)c3w[oc * 576 + rr * 3 + kw] : (__bf16)0.f;
    }
    if (gid < 32) {
        float s = g1[gid] * rsqrtf(v1[gid] + 1e-5f);
        sc1[gid] = s; sh1[gid] = (c1b[gid] - m1[gid]) * s + b1[gid];
    } else if (gid < 96) {
        int i = gid - 32;
        float s = g2[i] * rsqrtf(v2[i] + 1e-5f);
        sc2[i] = s; sh2[i] = (c2b[i] - m2[i]) * s + b2[i];
    } else if (gid < 224) {
        int i = gid - 96;
        float s = g3[i] * rsqrtf(v3[i] + 1e-5f);
        sc3[i] = s; sh3[i] = (c3b[i] - m3[i]) * s + b3[i];
    }
}

// ============ bf16 MFMA implicit-GEMM conv, row-vector gathers ============
// D[oc][s] = sum_k W[oc][k'] * im2col[k'][s], k' row-padded: row rr=(ic*KS+kh)
// has RW slots (KS real + zero-weight pad). A thread stages 16 consecutive k'
// = 16/RW whole rows = contiguous unpredicated dword loads at compile-time
// offsets. Input pointer xo has >=64 (conv2/3) / >=1024 (conv1) elements of
// slack both sides; invalid elements masked by ihok bit + low-kw clears.
template<typename OUTT, int IC, int KS, int RW, int S, int P,
         int IH, int IW, int OH, int OW, int OC, int KTP, int KOFF, int KCH,
         bool EPI>
__global__ __launch_bounds__(256, 6) void conv_mfma_kernel(
    const __bf16* __restrict__ xo,    // origin (odd element idx => rows 4B-aligned)
    const __bf16* __restrict__ wb,    // (OC,KTP) bf16, row-padded
    const float* __restrict__ scale,
    const float* __restrict__ shift,
    OUTT* __restrict__ out)           // (N,OC,OH,OW)
{
    constexpr int KITER = KCH / 32;
    static_assert(KCH % 32 == 0, "KCH");
    constexpr int OHW = OH * OW;
    constexpr int IHW = IH * IW;
    constexpr int LDR = 40;           // halfs per LDS row
    constexpr int NROW = 16 / RW;     // rows staged per thread per chunk
    constexpr int RU = RW / 2;        // uints per row

    __shared__ __attribute__((aligned(16))) __bf16 Is[128 * LDR];
    __shared__ __attribute__((aligned(16))) __bf16 Ws[32 * LDR];

    const int tid = threadIdx.x;
    const int sb0 = blockIdx.x * 128;
    const int oc0 = blockIdx.y * 32;

    const int sm = tid & 127;
    const int kpb = tid >> 7;         // wave-uniform half select
    int a_n, a_ih0, a_iw0;
    {
        int m = sb0 + sm;
        a_n = m / OHW;
        int rem = m % OHW;
        a_ih0 = (rem / OW) * S - P;
        a_iw0 = (rem % OW) * S - P;
    }
    unsigned ihok = 0;
    #pragma unroll
    for (int t = 0; t < KS; ++t)
        ihok |= (unsigned)(((a_ih0 + t) >= 0) && ((a_ih0 + t) < IH)) << t;
    const int iwlow = a_iw0 < 0 ? -a_iw0 : 0;   // kws [0,iwlow) invalid; <= P
    const __bf16* xp = xo + ((size_t)a_n * IC * IHW + (ptrdiff_t)a_ih0 * IW + a_iw0);

    const int w_oc = tid >> 2;        // 0..31 for tid<128
    const int w_j  = tid & 3;

    const int wave = tid >> 6, lane = tid & 63;
    const int quad = lane >> 4, l16 = lane & 15;

    f32x4 acc[2][2] = {};

    #pragma unroll
    for (int ci = 0; ci < KITER; ++ci) {
        const int k0 = KOFF + ci * 32;

        // ---- gather NROW whole rows, unpredicated dword loads ----
        union { unsigned u[8]; bf16x8 v[2]; } Pk;
        #pragma unroll
        for (int half = 0; half < 2; ++half) {
            if (kpb == half) {
                #pragma unroll
                for (int r = 0; r < NROW; ++r) {
                    const int rr = (k0 / RW) + half * NROW + r;   // folds to const
                    if (rr >= IC * KS) {
                        #pragma unroll
                        for (int q = 0; q < RU; ++q) Pk.u[r * RU + q] = 0u;
                    } else {
                        const int ic = rr / KS, kh = rr % KS;     // const after unroll
                        const unsigned* rp =
                            (const unsigned*)(xp + (ic * IHW + kh * IW));
                        unsigned t[RU];
                        #pragma unroll
                        for (int q = 0; q < RU; ++q) t[q] = rp[q];
                        bool rok = (ihok >> kh) & 1u;
                        #pragma unroll
                        for (int q = 0; q < RU; ++q) t[q] = rok ? t[q] : 0u;
                        #pragma unroll
                        for (int j = 0; j < P; ++j) {             // low-kw clears
                            unsigned msk = (j & 1) ? 0x0000FFFFu : 0xFFFF0000u;
                            t[j >> 1] = (j < iwlow) ? (t[j >> 1] & msk) : t[j >> 1];
                        }
                        #pragma unroll
                        for (int q = 0; q < RU; ++q) Pk.u[r * RU + q] = t[q];
                    }
                }
            }
        }
        // ---- weight gather (threads 0..127) ----
        bf16x8 wv = {};
        if (tid < 128)
            wv = *(const bf16x8*)&wb[(size_t)(oc0 + w_oc) * KTP + k0 + w_j * 8];

        __syncthreads();   // prev chunk's frag reads done before overwrite
        *(bf16x8*)&Is[sm * LDR + kpb * 16]     = Pk.v[0];
        *(bf16x8*)&Is[sm * LDR + kpb * 16 + 8] = Pk.v[1];
        if (tid < 128) *(bf16x8*)&Ws[w_oc * LDR + w_j * 8] = wv;
        __syncthreads();

        // ---- 4 MFMA: 32oc x 32s per wave ----
        bf16x8 afr[2], bfr[2];
        #pragma unroll
        for (int mt = 0; mt < 2; ++mt)
            afr[mt] = *(const bf16x8*)&Ws[(mt * 16 + l16) * LDR + quad * 8];
        #pragma unroll
        for (int nt = 0; nt < 2; ++nt)
            bfr[nt] = *(const bf16x8*)&Is[(wave * 32 + nt * 16 + l16) * LDR + quad * 8];
        #pragma unroll
        for (int mt = 0; mt < 2; ++mt)
            #pragma unroll
            for (int nt = 0; nt < 2; ++nt)
                acc[mt][nt] = __builtin_amdgcn_mfma_f32_16x16x32_bf16(
                    afr[mt], bfr[nt], acc[mt][nt], 0, 0, 0);
    }

    // ---- epilogue: D row = oc (quad*4+r), col = spatial (l16) ----
    #pragma unroll
    for (int mt = 0; mt < 2; ++mt) {
        #pragma unroll
        for (int r = 0; r < 4; ++r) {
            int oc = oc0 + mt * 16 + quad * 4 + r;
            float scl = EPI ? scale[oc] : 0.f;
            float shf = EPI ? shift[oc] : 0.f;
            #pragma unroll
            for (int nt = 0; nt < 2; ++nt) {
                int sg = sb0 + wave * 32 + nt * 16 + l16;
                int n = sg / OHW, s = sg % OHW;
                float v = acc[mt][nt][r];
                if (EPI) {
                    v = fmaf(v, scl, shf);
                    v = v > 0.f ? v : 0.f;
                }
                out[((size_t)n * OC + oc) * OHW + s] = (OUTT)v;
            }
        }
    }
}

// ============ pool: sum split-K partials + BN3 + ReLU + 7x7 avg ============
__global__ __launch_bounds__(256) void pool_bn_kernel(
    const float* __restrict__ p3a, const float* __restrict__ p3b,
    const float* __restrict__ sc3, const float* __restrict__ sh3,
    float* __restrict__ f)               // (N,512)
{
    int idx = blockIdx.x * 256 + threadIdx.x;
    int b = idx >> 9, p = idx & 511;
    int c = p >> 2, i = (p >> 1) & 1, j = p & 1;
    size_t base = ((size_t)b * 128 + c) * 196 + (i * 7) * 14 + j * 7;
    float scl = sc3[c], shf = sh3[c];
    float s = 0.f;
    #pragma unroll
    for (int u = 0; u < 7; ++u)
        #pragma unroll
        for (int v = 0; v < 7; ++v) {
            size_t k = base + u * 14 + v;
            float val = fmaf(p3a[k] + p3b[k], scl, shf);
            s += val > 0.f ? val : 0.f;
        }
    f[idx] = s * (1.f / 49.f);
}

// ============ quantum gate helpers ============
DEV void gate_ry(float* re, float* im, int q, float th) {
    float c = cosf(th * 0.5f), s = sinf(th * 0.5f);
    int mask = 8 >> q;
    for (int i = 0; i < 16; ++i) {
        if (i & mask) continue;
        int j = i | mask;
        float r0 = re[i], i0 = im[i], r1 = re[j], i1 = im[j];
        re[i] = c * r0 - s * r1;  im[i] = c * i0 - s * i1;
        re[j] = s * r0 + c * r1;  im[j] = s * i0 + c * i1;
    }
}
DEV void gate_rx(float* re, float* im, int q, float th) {
    float c = cosf(th * 0.5f), s = sinf(th * 0.5f);
    int mask = 8 >> q;
    for (int i = 0; i < 16; ++i) {
        if (i & mask) continue;
        int j = i | mask;
        float r0 = re[i], i0 = im[i], r1 = re[j], i1 = im[j];
        re[i] = c * r0 + s * i1;  im[i] = c * i0 - s * r1;
        re[j] = s * i0 + c * r1;  im[j] = -s * r0 + c * i1;
    }
}
DEV void gate_rz(float* re, float* im, int q, float th) {
    float c = cosf(th * 0.5f), s = sinf(th * 0.5f);
    int mask = 8 >> q;
    for (int i = 0; i < 16; ++i) {
        float sg = (i & mask) ? s : -s;
        float r = re[i], m = im[i];
        re[i] = c * r - sg * m;
        im[i] = c * m + sg * r;
    }
}
DEV void gate_cnot(float* re, float* im, int c, int t) {
    int cm = 8 >> c, tm = 8 >> t;
    for (int i = 0; i < 16; ++i) {
        if ((i & cm) && !(i & tm)) {
            int j = i | tm;
            float r = re[i]; re[i] = re[j]; re[j] = r;
            float m = im[i]; im[i] = im[j]; im[j] = m;
        }
    }
}

// ============ head: linear/tanh -> circuit -> MLP ============
__global__ __launch_bounds__(256) void head_kernel(
    const float* __restrict__ fpool,     // (N,512)
    const float* __restrict__ pre_w, const float* __restrict__ pre_b,
    const float* __restrict__ qw,
    const float* __restrict__ pw1, const float* __restrict__ pb1,
    const float* __restrict__ pw2, const float* __restrict__ pb2,
    float* __restrict__ out)             // (N,5)
{
    __shared__ float f[512];
    __shared__ float ang[4];
    __shared__ float sre[16], simg[16];
    __shared__ float zexp[4];
    __shared__ float h1[64];

    int b = blockIdx.x;
    int t = threadIdx.x;

    for (int p = t; p < 512; p += 256) f[p] = fpool[b * 512 + p];
    __syncthreads();

    int wv = t >> 6, lane = t & 63;
    float partial = 0.f;
    for (int d = lane; d < 512; d += 64)
        partial += f[d] * pre_w[wv * 512 + d];
    #pragma unroll
    for (int off = 32; off > 0; off >>= 1)
        partial += __shfl_down(partial, off, 64);
    if (lane == 0)
        ang[wv] = tanhf(partial + pre_b[wv]) * 3.14159265358979323846f;
    __syncthreads();

    if (t == 0) {
        for (int i = 0; i < 16; ++i) { sre[i] = 0.f; simg[i] = 0.f; }
        sre[0] = 1.f;
        for (int q = 0; q < 4; ++q) gate_ry(sre, simg, q, ang[q]);
        for (int l = 0; l < 2; ++l) {
            for (int q = 0; q < 4; ++q) {
                const float* qq = qw + (l * 4 + q) * 3;
                gate_rx(sre, simg, q, qq[0]);
                gate_ry(sre, simg, q, qq[1]);
                gate_rz(sre, simg, q, qq[2]);
            }
            gate_cnot(sre, simg, 0, 1);
            gate_cnot(sre, simg, 1, 2);
            gate_cnot(sre, simg, 2, 3);
            gate_cnot(sre, simg, 3, 0);
        }
        for (int q = 0; q < 4; ++q) {
            float z = 0.f;
            for (int i = 0; i < 16; ++i) {
                float p2 = sre[i] * sre[i] + simg[i] * simg[i];
                z += (((i >> (3 - q)) & 1) ? -p2 : p2);
            }
            zexp[q] = z;
        }
    }
    __syncthreads();

    if (t < 64) {
        float s = pb1[t];
        #pragma unroll
        for (int k = 0; k < 4; ++k) s += zexp[k] * pw1[t * 4 + k];
        h1[t] = s > 0.f ? s : 0.f;
    }
    __syncthreads();

    if (t < 5) {
        float s = pb2[t];
        for (int k = 0; k < 64; ++k) s += h1[k] * pw2[t * 64 + k];
        out[b * 5 + t] = s;
    }
}

extern "C" void kernel_launch(void* const* d_in, const int* in_sizes, int n_in,
                              void* d_out, int out_size, void* d_ws, size_t ws_size,
                              hipStream_t stream) {
    const float* x    = (const float*)d_in[0];
    const float* c1w  = (const float*)d_in[1];
    const float* c1b  = (const float*)d_in[2];
    const float* bn1g = (const float*)d_in[3];
    const float* bn1b = (const float*)d_in[4];
    const float* bn1m = (const float*)d_in[5];
    const float* bn1v = (const float*)d_in[6];
    const float* c2w  = (const float*)d_in[7];
    const float* c2b  = (const float*)d_in[8];
    const float* bn2g = (const float*)d_in[9];
    const float* bn2b = (const float*)d_in[10];
    const float* bn2m = (const float*)d_in[11];
    const float* bn2v = (const float*)d_in[12];
    const float* c3w  = (const float*)d_in[13];
    const float* c3bi = (const float*)d_in[14];
    const float* bn3g = (const float*)d_in[15];
    const float* bn3b = (const float*)d_in[16];
    const float* bn3m = (const float*)d_in[17];
    const float* bn3v = (const float*)d_in[18];
    const float* prw  = (const float*)d_in[19];
    const float* prb  = (const float*)d_in[20];
    const float* qw   = (const float*)d_in[21];
    const float* pw1  = (const float*)d_in[22];
    const float* pb1  = (const float*)d_in[23];
    const float* pw2  = (const float*)d_in[24];
    const float* pb2  = (const float*)d_in[25];

    const int N = in_sizes[0] / (3 * 224 * 224);   // 128
    const long NX  = (long)N * 3 * 224 * 224;      // 19,267,584
    const size_t NC1 = (size_t)N * 32 * 56 * 56;   // 12,845,056
    const size_t NC2 = (size_t)N * 64 * 28 * 28;   //  6,422,528

    // ---- workspace layout (halfs) ----
    __bf16* ws_h = (__bf16*)d_ws;
    __bf16* xpad_alloc = ws_h;                     // NX + 2048
    __bf16* xpad_o = xpad_alloc + 1023;            // odd origin: rows 4B-aligned
    __bf16* c1o_alloc = xpad_alloc + NX + 2048;
    __bf16* c1o_o = c1o_alloc + 63;                // odd origin
    __bf16* c2o_alloc = c1o_alloc + NC1 + 128;
    __bf16* c2o_o = c2o_alloc + 63;
    __bf16* wb1 = c2o_alloc + NC2 + 128;           // 32*192
    __bf16* wb2 = wb1 + 32 * 192;                  // 64*384
    __bf16* wb3 = wb2 + 64 * 384;                  // 128*768
    float* sc1 = (float*)(wb3 + 128 * 768);
    float* sh1 = sc1 + 32;
    float* sc2 = sh1 + 32;  float* sh2 = sc2 + 64;
    float* sc3 = sh2 + 64;  float* sh3 = sc3 + 128;
    float* fpool = sh3 + 128;                      // N*512 floats
    // conv3 fp32 partials alias xpad (dead after conv1): 25.7MB <= 38.5MB
    float* p3a = (float*)xpad_alloc;
    float* p3b = p3a + (size_t)N * 128 * 14 * 14;

    prep_all<<<1024, 256, 0, stream>>>(
        x, NX,
        c1w, c1b, bn1g, bn1b, bn1m, bn1v,
        c2w, c2b, bn2g, bn2b, bn2m, bn2v,
        c3w, c3bi, bn3g, bn3b, bn3m, bn3v,
        xpad_o, wb1, wb2, wb3, sc1, sh1, sc2, sh2, sc3, sh3);

    // conv1: rows of 8 (KS=7), KTP=KCH=192 (6 chunks), 3136 blocks
    conv_mfma_kernel<__bf16, 3, 7, 8, 4, 3, 224, 224, 56, 56, 32, 192, 0, 192, true>
        <<<dim3(401408 / 128, 1), 256, 0, stream>>>(xpad_o, wb1, sc1, sh1, c1o_o);
    // conv2: rows of 4 (KS=3), KTP=KCH=384 (12 chunks), (784,2) blocks
    conv_mfma_kernel<__bf16, 32, 3, 4, 2, 1, 56, 56, 28, 28, 64, 384, 0, 384, true>
        <<<dim3(100352 / 128, 2), 256, 0, stream>>>(c1o_o, wb2, sc2, sh2, c2o_o);
    // conv3: rows of 4, KTP=768, split-K as two constexpr-offset launches
    conv_mfma_kernel<float, 64, 3, 4, 2, 1, 28, 28, 14, 14, 128, 768, 0, 384, false>
        <<<dim3(25088 / 128, 4), 256, 0, stream>>>(c2o_o, wb3, sc3, sh3, p3a);
    conv_mfma_kernel<float, 64, 3, 4, 2, 1, 28, 28, 14, 14, 128, 768, 384, 384, false>
        <<<dim3(25088 / 128, 4), 256, 0, stream>>>(c2o_o, wb3, sc3, sh3, p3b);

    pool_bn_kernel<<<(N * 512) / 256, 256, 0, stream>>>(p3a, p3b, sc3, sh3, fpool);
    head_kernel<<<N, 256, 0, stream>>>(fpool, prw, prb, qw,
                                       pw1, pb1, pw2, pb2, (float*)d_out);
}

// Round 10
// 250.948 us; speedup vs baseline: 1.4067x; 1.0720x over previous
//
#include <hip/hip_runtime.h>
#include <math.h>

#define DEV __device__ __forceinline__

typedef __attribute__((ext_vector_type(8))) __bf16 bf16x8;
typedef __attribute__((ext_vector_type(4))) float f32x4;

// ============ prep: x fp32->bf16 (vectorized); weights slot-shifted bf16; BN fold ============
// Weight rows padded to RW with the real KS weights at slots 1..KS (slot 0 = 0):
// im2col row loads then start at a_iw0-1 (even element => 4B-aligned rows) and
// the garbage element 0 is killed by the zero weight.
__global__ void prep_all(
    const float* __restrict__ x, long nx8,
    const float* __restrict__ c1w, const float* __restrict__ c1b,
    const float* __restrict__ g1, const float* __restrict__ b1,
    const float* __restrict__ m1, const float* __restrict__ v1,
    const float* __restrict__ c2w, const float* __restrict__ c2b,
    const float* __restrict__ g2, const float* __restrict__ b2,
    const float* __restrict__ m2, const float* __restrict__ v2,
    const float* __restrict__ c3w, const float* __restrict__ c3b,
    const float* __restrict__ g3, const float* __restrict__ b3,
    const float* __restrict__ m3, const float* __restrict__ v3,
    __bf16* __restrict__ xpad,            // 16B-aligned
    __bf16* __restrict__ wb1, __bf16* __restrict__ wb2, __bf16* __restrict__ wb3,
    float* __restrict__ sc1, float* __restrict__ sh1,
    float* __restrict__ sc2, float* __restrict__ sh2,
    float* __restrict__ sc3, float* __restrict__ sh3)
{
    long gid = (long)blockIdx.x * 256 + threadIdx.x;
    long gs = (long)gridDim.x * 256;
    const float4* x4 = (const float4*)x;
    bf16x8* xp8 = (bf16x8*)xpad;
    for (long e = gid; e < nx8; e += gs) {
        float4 a = x4[2 * e], b = x4[2 * e + 1];
        bf16x8 o;
        o[0] = (__bf16)a.x; o[1] = (__bf16)a.y; o[2] = (__bf16)a.z; o[3] = (__bf16)a.w;
        o[4] = (__bf16)b.x; o[5] = (__bf16)b.y; o[6] = (__bf16)b.z; o[7] = (__bf16)b.w;
        xp8[e] = o;
    }

    // wb1: [32][192], rows of 8; slots 1..7 real (rr<21)
    for (long e = gid; e < 32 * 192; e += gs) {
        int oc = e / 192, k = e % 192, rr = k >> 3, kw = k & 7;
        wb1[e] = (rr < 21 && kw >= 1) ? (__bf16)c1w[oc * 147 + rr * 7 + kw - 1]
                                      : (__bf16)0.f;
    }
    // wb2: [64][384], rows of 4; slots 1..3 real
    for (long e = gid; e < 64 * 384; e += gs) {
        int oc = e / 384, k = e % 384, rr = k >> 2, kw = k & 3;
        wb2[e] = (kw >= 1) ? (__bf16)c2w[oc * 288 + rr * 3 + kw - 1] : (__bf16)0.f;
    }
    // wb3: [128][768], rows of 4; slots 1..3 real
    for (long e = gid; e < 128 * 768; e += gs) {
        int oc = e / 768, k = e % 768, rr = k >> 2, kw = k & 3;
        wb3[e] = (kw >= 1) ? (__bf16)c3w[oc * 576 + rr * 3 + kw - 1] : (__bf16)0.f;
    }
    if (gid < 32) {
        float s = g1[gid] * rsqrtf(v1[gid] + 1e-5f);
        sc1[gid] = s; sh1[gid] = (c1b[gid] - m1[gid]) * s + b1[gid];
    } else if (gid < 96) {
        int i = gid - 32;
        float s = g2[i] * rsqrtf(v2[i] + 1e-5f);
        sc2[i] = s; sh2[i] = (c2b[i] - m2[i]) * s + b2[i];
    } else if (gid < 224) {
        int i = gid - 96;
        float s = g3[i] * rsqrtf(v3[i] + 1e-5f);
        sc3[i] = s; sh3[i] = (c3b[i] - m3[i]) * s + b3[i];
    }
}

// ============ bf16 MFMA implicit-GEMM conv body ============
// D[oc][s] = sum_k' W[oc][k'] * im2col[k'][s], k' row-padded (slot-shifted).
// Block: 32 oc x 128 spatial, BK=32, 4 waves. KOFF compile-time.
template<typename OUTT, int IC, int KS, int RW, int S, int P,
         int IH, int IW, int OH, int OW, int OC, int KTP, int KOFF, int KCH,
         bool EPI>
DEV void conv_body(
    const __bf16* __restrict__ xo,    // logical base; >= (P*IW+P+1) halfs slack before
    const __bf16* __restrict__ wb,    // (OC,KTP) bf16, slot-shifted rows
    const float* __restrict__ scale,
    const float* __restrict__ shift,
    OUTT* __restrict__ out,           // (N,OC,OH,OW)
    __bf16* Is, __bf16* Ws)           // LDS: 128*LDR, 32*LDR halfs
{
    constexpr int KITER = KCH / 32;
    static_assert(KCH % 32 == 0, "KCH");
    constexpr int OHW = OH * OW;
    constexpr int IHW = IH * IW;
    constexpr int LDR = 40;
    constexpr int NROW = 16 / RW;     // rows staged per thread per chunk
    constexpr int RU = RW / 2;        // dwords per row

    const int tid = threadIdx.x;
    const int sb0 = blockIdx.x * 128;
    const int oc0 = blockIdx.y * 32;

    const int sm = tid & 127;
    const int kpb = tid >> 7;         // wave-uniform half select
    int a_n, a_ih0, a_iw0;
    {
        int m = sb0 + sm;
        a_n = m / OHW;
        int rem = m % OHW;
        a_ih0 = (rem / OW) * S - P;
        a_iw0 = (rem % OW) * S - P;
    }
    unsigned ihok = 0;
    #pragma unroll
    for (int t = 0; t < KS; ++t)
        ihok |= (unsigned)(((a_ih0 + t) >= 0) && ((a_ih0 + t) < IH)) << t;
    const bool left = (a_iw0 < 0);    // only ow==0; clears elements 1..P
    const __bf16* xp = xo + ((size_t)a_n * IC * IHW + (ptrdiff_t)a_ih0 * IW
                             + (a_iw0 - 1));   // even element => 4B-aligned rows

    const int w_oc = tid >> 2;        // 0..31 for tid<128
    const int w_j  = tid & 3;

    const int wave = tid >> 6, lane = tid & 63;
    const int quad = lane >> 4, l16 = lane & 15;

    f32x4 acc[2][2] = {};

    #pragma unroll
    for (int ci = 0; ci < KITER; ++ci) {
        const int k0 = KOFF + ci * 32;

        // ---- gather NROW whole rows, unpredicated dword loads ----
        union { unsigned u[8]; bf16x8 v[2]; } Pk;
        #pragma unroll
        for (int r = 0; r < NROW; ++r) {
            const int rr = (k0 / RW) + kpb * NROW + r;    // compile-time
            if (rr >= IC * KS) {
                #pragma unroll
                for (int q = 0; q < RU; ++q) Pk.u[r * RU + q] = 0u;
            } else {
                const int ic = rr / KS, kh = rr % KS;     // compile-time
                const unsigned* rp = (const unsigned*)(xp + (ic * IHW + kh * IW));
                unsigned t[RU];
                #pragma unroll
                for (int q = 0; q < RU; ++q) t[q] = rp[q];
                bool rok = (ihok >> kh) & 1u;
                #pragma unroll
                for (int q = 0; q < RU; ++q) t[q] = rok ? t[q] : 0u;
                // left-edge clears: elements 1..P (element 0 zero-weighted)
                t[0] = left ? (t[0] & 0x0000FFFFu) : t[0];
                if constexpr (P >= 2) t[1] = left ? 0u : t[1];
                #pragma unroll
                for (int q = 0; q < RU; ++q) Pk.u[r * RU + q] = t[q];
            }
        }
        // ---- weight gather (threads 0..127) ----
        bf16x8 wv = {};
        if (tid < 128)
            wv = *(const bf16x8*)&wb[(size_t)(oc0 + w_oc) * KTP + k0 + w_j * 8];

        __syncthreads();   // prev chunk's frag reads done before overwrite
        *(bf16x8*)&Is[sm * LDR + kpb * 16]     = Pk.v[0];
        *(bf16x8*)&Is[sm * LDR + kpb * 16 + 8] = Pk.v[1];
        if (tid < 128) *(bf16x8*)&Ws[w_oc * LDR + w_j * 8] = wv;
        __syncthreads();

        // ---- 4 MFMA: 32oc x 32s per wave ----
        bf16x8 afr[2], bfr[2];
        #pragma unroll
        for (int mt = 0; mt < 2; ++mt)
            afr[mt] = *(const bf16x8*)&Ws[(mt * 16 + l16) * LDR + quad * 8];
        #pragma unroll
        for (int nt = 0; nt < 2; ++nt)
            bfr[nt] = *(const bf16x8*)&Is[(wave * 32 + nt * 16 + l16) * LDR + quad * 8];
        #pragma unroll
        for (int mt = 0; mt < 2; ++mt)
            #pragma unroll
            for (int nt = 0; nt < 2; ++nt)
                acc[mt][nt] = __builtin_amdgcn_mfma_f32_16x16x32_bf16(
                    afr[mt], bfr[nt], acc[mt][nt], 0, 0, 0);
    }

    // ---- epilogue: D row = oc (quad*4+r), col = spatial (l16) ----
    #pragma unroll
    for (int mt = 0; mt < 2; ++mt) {
        #pragma unroll
        for (int r = 0; r < 4; ++r) {
            int oc = oc0 + mt * 16 + quad * 4 + r;
            float scl = EPI ? scale[oc] : 0.f;
            float shf = EPI ? shift[oc] : 0.f;
            #pragma unroll
            for (int nt = 0; nt < 2; ++nt) {
                int sg = sb0 + wave * 32 + nt * 16 + l16;
                int n = sg / OHW, s = sg % OHW;
                float v = acc[mt][nt][r];
                if (EPI) {
                    v = fmaf(v, scl, shf);
                    v = v > 0.f ? v : 0.f;
                }
                out[((size_t)n * OC + oc) * OHW + s] = (OUTT)v;
            }
        }
    }
}

template<typename OUTT, int IC, int KS, int RW, int S, int P,
         int IH, int IW, int OH, int OW, int OC, int KTP, int KCH, bool EPI>
__global__ __launch_bounds__(256, 6) void conv_mfma_kernel(
    const __bf16* __restrict__ xo, const __bf16* __restrict__ wb,
    const float* __restrict__ scale, const float* __restrict__ shift,
    OUTT* __restrict__ out)
{
    __shared__ __attribute__((aligned(16))) __bf16 Is[128 * 40];
    __shared__ __attribute__((aligned(16))) __bf16 Ws[32 * 40];
    conv_body<OUTT, IC, KS, RW, S, P, IH, IW, OH, OW, OC, KTP, 0, KCH, EPI>(
        xo, wb, scale, shift, out, Is, Ws);
}

// conv3 merged: blockIdx.z selects the compile-time K-offset instantiation
__global__ __launch_bounds__(256, 6) void conv3_kernel(
    const __bf16* __restrict__ xo, const __bf16* __restrict__ wb,
    float* __restrict__ p3a, float* __restrict__ p3b)
{
    __shared__ __attribute__((aligned(16))) __bf16 Is[128 * 40];
    __shared__ __attribute__((aligned(16))) __bf16 Ws[32 * 40];
    if (blockIdx.z == 0)
        conv_body<float, 64, 3, 4, 2, 1, 28, 28, 14, 14, 128, 768, 0, 384, false>(
            xo, wb, nullptr, nullptr, p3a, Is, Ws);
    else
        conv_body<float, 64, 3, 4, 2, 1, 28, 28, 14, 14, 128, 768, 384, 384, false>(
            xo, wb, nullptr, nullptr, p3b, Is, Ws);
}

// ============ pool: sum split-K partials + BN3 + ReLU + 7x7 avg ============
__global__ __launch_bounds__(256) void pool_bn_kernel(
    const float* __restrict__ p3a, const float* __restrict__ p3b,
    const float* __restrict__ sc3, const float* __restrict__ sh3,
    float* __restrict__ f)               // (N,512)
{
    int idx = blockIdx.x * 256 + threadIdx.x;
    int b = idx >> 9, p = idx & 511;
    int c = p >> 2, i = (p >> 1) & 1, j = p & 1;
    size_t base = ((size_t)b * 128 + c) * 196 + (i * 7) * 14 + j * 7;
    float scl = sc3[c], shf = sh3[c];
    float s = 0.f;
    #pragma unroll
    for (int u = 0; u < 7; ++u)
        #pragma unroll
        for (int v = 0; v < 7; ++v) {
            size_t k = base + u * 14 + v;
            float val = fmaf(p3a[k] + p3b[k], scl, shf);
            s += val > 0.f ? val : 0.f;
        }
    f[idx] = s * (1.f / 49.f);
}

// ============ quantum gate helpers ============
DEV void gate_ry(float* re, float* im, int q, float th) {
    float c = cosf(th * 0.5f), s = sinf(th * 0.5f);
    int mask = 8 >> q;
    for (int i = 0; i < 16; ++i) {
        if (i & mask) continue;
        int j = i | mask;
        float r0 = re[i], i0 = im[i], r1 = re[j], i1 = im[j];
        re[i] = c * r0 - s * r1;  im[i] = c * i0 - s * i1;
        re[j] = s * r0 + c * r1;  im[j] = s * i0 + c * i1;
    }
}
DEV void gate_rx(float* re, float* im, int q, float th) {
    float c = cosf(th * 0.5f), s = sinf(th * 0.5f);
    int mask = 8 >> q;
    for (int i = 0; i < 16; ++i) {
        if (i & mask) continue;
        int j = i | mask;
        float r0 = re[i], i0 = im[i], r1 = re[j], i1 = im[j];
        re[i] = c * r0 + s * i1;  im[i] = c * i0 - s * r1;
        re[j] = s * i0 + c * r1;  im[j] = -s * r0 + c * i1;
    }
}
DEV void gate_rz(float* re, float* im, int q, float th) {
    float c = cosf(th * 0.5f), s = sinf(th * 0.5f);
    int mask = 8 >> q;
    for (int i = 0; i < 16; ++i) {
        float sg = (i & mask) ? s : -s;
        float r = re[i], m = im[i];
        re[i] = c * r - sg * m;
        im[i] = c * m + sg * r;
    }
}
DEV void gate_cnot(float* re, float* im, int c, int t) {
    int cm = 8 >> c, tm = 8 >> t;
    for (int i = 0; i < 16; ++i) {
        if ((i & cm) && !(i & tm)) {
            int j = i | tm;
            float r = re[i]; re[i] = re[j]; re[j] = r;
            float m = im[i]; im[i] = im[j]; im[j] = m;
        }
    }
}

// ============ head: linear/tanh -> circuit -> MLP ============
__global__ __launch_bounds__(256) void head_kernel(
    const float* __restrict__ fpool,     // (N,512)
    const float* __restrict__ pre_w, const float* __restrict__ pre_b,
    const float* __restrict__ qw,
    const float* __restrict__ pw1, const float* __restrict__ pb1,
    const float* __restrict__ pw2, const float* __restrict__ pb2,
    float* __restrict__ out)             // (N,5)
{
    __shared__ float f[512];
    __shared__ float ang[4];
    __shared__ float sre[16], simg[16];
    __shared__ float zexp[4];
    __shared__ float h1[64];

    int b = blockIdx.x;
    int t = threadIdx.x;

    for (int p = t; p < 512; p += 256) f[p] = fpool[b * 512 + p];
    __syncthreads();

    int wv = t >> 6, lane = t & 63;
    float partial = 0.f;
    for (int d = lane; d < 512; d += 64)
        partial += f[d] * pre_w[wv * 512 + d];
    #pragma unroll
    for (int off = 32; off > 0; off >>= 1)
        partial += __shfl_down(partial, off, 64);
    if (lane == 0)
        ang[wv] = tanhf(partial + pre_b[wv]) * 3.14159265358979323846f;
    __syncthreads();

    if (t == 0) {
        for (int i = 0; i < 16; ++i) { sre[i] = 0.f; simg[i] = 0.f; }
        sre[0] = 1.f;
        for (int q = 0; q < 4; ++q) gate_ry(sre, simg, q, ang[q]);
        for (int l = 0; l < 2; ++l) {
            for (int q = 0; q < 4; ++q) {
                const float* qq = qw + (l * 4 + q) * 3;
                gate_rx(sre, simg, q, qq[0]);
                gate_ry(sre, simg, q, qq[1]);
                gate_rz(sre, simg, q, qq[2]);
            }
            gate_cnot(sre, simg, 0, 1);
            gate_cnot(sre, simg, 1, 2);
            gate_cnot(sre, simg, 2, 3);
            gate_cnot(sre, simg, 3, 0);
        }
        for (int q = 0; q < 4; ++q) {
            float z = 0.f;
            for (int i = 0; i < 16; ++i) {
                float p2 = sre[i] * sre[i] + simg[i] * simg[i];
                z += (((i >> (3 - q)) & 1) ? -p2 : p2);
            }
            zexp[q] = z;
        }
    }
    __syncthreads();

    if (t < 64) {
        float s = pb1[t];
        #pragma unroll
        for (int k = 0; k < 4; ++k) s += zexp[k] * pw1[t * 4 + k];
        h1[t] = s > 0.f ? s : 0.f;
    }
    __syncthreads();

    if (t < 5) {
        float s = pb2[t];
        for (int k = 0; k < 64; ++k) s += h1[k] * pw2[t * 64 + k];
        out[b * 5 + t] = s;
    }
}

extern "C" void kernel_launch(void* const* d_in, const int* in_sizes, int n_in,
                              void* d_out, int out_size, void* d_ws, size_t ws_size,
                              hipStream_t stream) {
    const float* x    = (const float*)d_in[0];
    const float* c1w  = (const float*)d_in[1];
    const float* c1b  = (const float*)d_in[2];
    const float* bn1g = (const float*)d_in[3];
    const float* bn1b = (const float*)d_in[4];
    const float* bn1m = (const float*)d_in[5];
    const float* bn1v = (const float*)d_in[6];
    const float* c2w  = (const float*)d_in[7];
    const float* c2b  = (const float*)d_in[8];
    const float* bn2g = (const float*)d_in[9];
    const float* bn2b = (const float*)d_in[10];
    const float* bn2m = (const float*)d_in[11];
    const float* bn2v = (const float*)d_in[12];
    const float* c3w  = (const float*)d_in[13];
    const float* c3bi = (const float*)d_in[14];
    const float* bn3g = (const float*)d_in[15];
    const float* bn3b = (const float*)d_in[16];
    const float* bn3m = (const float*)d_in[17];
    const float* bn3v = (const float*)d_in[18];
    const float* prw  = (const float*)d_in[19];
    const float* prb  = (const float*)d_in[20];
    const float* qw   = (const float*)d_in[21];
    const float* pw1  = (const float*)d_in[22];
    const float* pb1  = (const float*)d_in[23];
    const float* pw2  = (const float*)d_in[24];
    const float* pb2  = (const float*)d_in[25];

    const int N = in_sizes[0] / (3 * 224 * 224);   // 128
    const long NX  = (long)N * 3 * 224 * 224;      // 19,267,584 (divisible by 8)
    const size_t NC1 = (size_t)N * 32 * 56 * 56;   // 12,845,056
    const size_t NC2 = (size_t)N * 64 * 28 * 28;   //  6,422,528

    // ---- workspace layout (halfs; every logical base is a multiple of 8) ----
    __bf16* ws_h = (__bf16*)d_ws;
    __bf16* xpad_alloc = ws_h;                     // 1024 slack + NX + 64
    __bf16* xpad = xpad_alloc + 1024;              // 16B-aligned
    __bf16* c1o_alloc = xpad_alloc + 1024 + NX + 64;
    __bf16* c1o = c1o_alloc + 64;
    __bf16* c2o_alloc = c1o_alloc + 64 + NC1 + 64;
    __bf16* c2o = c2o_alloc + 64;
    __bf16* wb1 = c2o_alloc + 64 + NC2 + 64;       // 32*192
    __bf16* wb2 = wb1 + 32 * 192;                  // 64*384
    __bf16* wb3 = wb2 + 64 * 384;                  // 128*768
    float* sc1 = (float*)(wb3 + 128 * 768);
    float* sh1 = sc1 + 32;
    float* sc2 = sh1 + 32;  float* sh2 = sc2 + 64;
    float* sc3 = sh2 + 64;  float* sh3 = sc3 + 128;
    float* fpool = sh3 + 128;                      // N*512 floats
    // conv3 fp32 partials alias xpad region (dead after conv1): 25.7MB <= 38.5MB
    float* p3a = (float*)xpad_alloc;
    float* p3b = p3a + (size_t)N * 128 * 14 * 14;

    prep_all<<<1024, 256, 0, stream>>>(
        x, NX / 8,
        c1w, c1b, bn1g, bn1b, bn1m, bn1v,
        c2w, c2b, bn2g, bn2b, bn2m, bn2v,
        c3w, c3bi, bn3g, bn3b, bn3m, bn3v,
        xpad, wb1, wb2, wb3, sc1, sh1, sc2, sh2, sc3, sh3);

    // conv1: rows of 8 (KS=7), KTP=KCH=192, 3136 blocks
    conv_mfma_kernel<__bf16, 3, 7, 8, 4, 3, 224, 224, 56, 56, 32, 192, 192, true>
        <<<dim3(401408 / 128, 1), 256, 0, stream>>>(xpad, wb1, sc1, sh1, c1o);
    // conv2: rows of 4 (KS=3), KTP=KCH=384, (784,2) blocks
    conv_mfma_kernel<__bf16, 32, 3, 4, 2, 1, 56, 56, 28, 28, 64, 384, 384, true>
        <<<dim3(100352 / 128, 2), 256, 0, stream>>>(c1o, wb2, sc2, sh2, c2o);
    // conv3: merged split-K, (196,4,2) = 1568 blocks in ONE dispatch
    conv3_kernel<<<dim3(25088 / 128, 4, 2), 256, 0, stream>>>(c2o, wb3, p3a, p3b);

    pool_bn_kernel<<<(N * 512) / 256, 256, 0, stream>>>(p3a, p3b, sc3, sh3, fpool);
    head_kernel<<<N, 256, 0, stream>>>(fpool, prw, prb, qw,
                                       pw1, pb1, pw2, pb2, (float*)d_out);
}

// Round 11
// 245.149 us; speedup vs baseline: 1.4400x; 1.0237x over previous
//
#include <hip/hip_runtime.h>
#include <math.h>

#define DEV __device__ __forceinline__

typedef __attribute__((ext_vector_type(8))) __bf16 bf16x8;
typedef __attribute__((ext_vector_type(4))) float f32x4;

// ============ prep: weights -> slot-shifted row-padded bf16; BN fold ============
// Weight rows padded to RW with real KS weights at slots 1..KS (slot 0 = 0).
__global__ void prep_weights(
    const float* __restrict__ c1w, const float* __restrict__ c1b,
    const float* __restrict__ g1, const float* __restrict__ b1,
    const float* __restrict__ m1, const float* __restrict__ v1,
    const float* __restrict__ c2w, const float* __restrict__ c2b,
    const float* __restrict__ g2, const float* __restrict__ b2,
    const float* __restrict__ m2, const float* __restrict__ v2,
    const float* __restrict__ c3w, const float* __restrict__ c3b,
    const float* __restrict__ g3, const float* __restrict__ b3,
    const float* __restrict__ m3, const float* __restrict__ v3,
    __bf16* __restrict__ wb1, __bf16* __restrict__ wb2, __bf16* __restrict__ wb3,
    float* __restrict__ sc1, float* __restrict__ sh1,
    float* __restrict__ sc2, float* __restrict__ sh2,
    float* __restrict__ sc3, float* __restrict__ sh3)
{
    int gid = blockIdx.x * 256 + threadIdx.x;
    int gs = gridDim.x * 256;
    // wb1: [32][192], rows of 8; slots 1..7 real (rr<21)
    for (int e = gid; e < 32 * 192; e += gs) {
        int oc = e / 192, k = e % 192, rr = k >> 3, kw = k & 7;
        wb1[e] = (rr < 21 && kw >= 1) ? (__bf16)c1w[oc * 147 + rr * 7 + kw - 1]
                                      : (__bf16)0.f;
    }
    // wb2: [64][384], rows of 4; slots 1..3 real
    for (int e = gid; e < 64 * 384; e += gs) {
        int oc = e / 384, k = e % 384, rr = k >> 2, kw = k & 3;
        wb2[e] = (kw >= 1) ? (__bf16)c2w[oc * 288 + rr * 3 + kw - 1] : (__bf16)0.f;
    }
    // wb3: [128][768], rows of 4; slots 1..3 real
    for (int e = gid; e < 128 * 768; e += gs) {
        int oc = e / 768, k = e % 768, rr = k >> 2, kw = k & 3;
        wb3[e] = (kw >= 1) ? (__bf16)c3w[oc * 576 + rr * 3 + kw - 1] : (__bf16)0.f;
    }
    if (gid < 32) {
        float s = g1[gid] * rsqrtf(v1[gid] + 1e-5f);
        sc1[gid] = s; sh1[gid] = (c1b[gid] - m1[gid]) * s + b1[gid];
    } else if (gid < 96) {
        int i = gid - 32;
        float s = g2[i] * rsqrtf(v2[i] + 1e-5f);
        sc2[i] = s; sh2[i] = (c2b[i] - m2[i]) * s + b2[i];
    } else if (gid < 224) {
        int i = gid - 96;
        float s = g3[i] * rsqrtf(v3[i] + 1e-5f);
        sc3[i] = s; sh3[i] = (c3b[i] - m3[i]) * s + b3[i];
    }
}

// ============ conv1: fp32 input read directly, convert in-register ============
// Rows of 8 fp32 (slot 0 pad, 1..7 = kw 0..6), 2x dwordx4 per row with
// max(off,0) clamps: clamped garbage only ever lands in slots that are
// zero-weighted (slot 0) or left-cleared (slots 1..3 at ow==0) or whole-row
// masked (rok==0) -- verified for the ic=0/ih-row=0/ow=0 corner.
__global__ __launch_bounds__(256, 6) void conv1_kernel(
    const float* __restrict__ x,      // (N,3,224,224) fp32
    const __bf16* __restrict__ wb,    // (32,192) slot-shifted
    const float* __restrict__ scale, const float* __restrict__ shift,
    __bf16* __restrict__ out)         // (N,32,56,56)
{
    constexpr int IHW = 224 * 224, OHW = 56 * 56, LDR = 40;
    __shared__ __attribute__((aligned(16))) __bf16 Is[128 * LDR];
    __shared__ __attribute__((aligned(16))) __bf16 Ws[32 * LDR];

    const int tid = threadIdx.x;
    const int sb0 = blockIdx.x * 128;
    const int sm = tid & 127;
    const int kpb = tid >> 7;

    int a_n, a_ih0, a_iw0;
    {
        int m = sb0 + sm;
        a_n = m / OHW;
        int rem = m % OHW;
        a_ih0 = (rem / 56) * 4 - 3;
        a_iw0 = (rem % 56) * 4 - 3;
    }
    unsigned ihok = 0;
    #pragma unroll
    for (int t = 0; t < 7; ++t)
        ihok |= (unsigned)(((a_ih0 + t) >= 0) && ((a_ih0 + t) < 224)) << t;
    const bool left = (a_iw0 < 0);
    const int boff = a_n * 3 * IHW + a_ih0 * 224 + (a_iw0 - 1);  // 16B-aligned

    const int w_oc = tid >> 2, w_j = tid & 3;
    const int wave = tid >> 6, lane = tid & 63;
    const int quad = lane >> 4, l16 = lane & 15;

    f32x4 acc[2][2] = {};

    #pragma unroll
    for (int ci = 0; ci < 6; ++ci) {
        const int k0 = ci * 32;
        bf16x8 hv[2];
        #pragma unroll
        for (int r = 0; r < 2; ++r) {
            const int rr = ci * 4 + kpb * 2 + r;          // compile-time
            if (rr >= 21) {
                hv[r] = (bf16x8){};
            } else {
                const int ic = rr / 7, kh = rr % 7;       // compile-time
                int off = boff + (ic * IHW + kh * 224);
                int o0 = off < 0 ? 0 : off;
                int o1 = (off + 4) < 0 ? 0 : (off + 4);
                float4 A = *(const float4*)(x + o0);
                float4 B = *(const float4*)(x + o1);
                float va[8] = {A.x, A.y, A.z, A.w, B.x, B.y, B.z, B.w};
                bool rok = (ihok >> kh) & 1u;
                #pragma unroll
                for (int j = 0; j < 8; ++j) va[j] = rok ? va[j] : 0.f;
                #pragma unroll
                for (int j = 1; j <= 3; ++j) va[j] = left ? 0.f : va[j];
                bf16x8 h;
                #pragma unroll
                for (int j = 0; j < 8; ++j) h[j] = (__bf16)va[j];
                hv[r] = h;
            }
        }
        bf16x8 wv = {};
        if (tid < 128)
            wv = *(const bf16x8*)&wb[(size_t)w_oc * 192 + k0 + w_j * 8];

        __syncthreads();
        *(bf16x8*)&Is[sm * LDR + kpb * 16]     = hv[0];
        *(bf16x8*)&Is[sm * LDR + kpb * 16 + 8] = hv[1];
        if (tid < 128) *(bf16x8*)&Ws[w_oc * LDR + w_j * 8] = wv;
        __syncthreads();

        bf16x8 afr[2], bfr[2];
        #pragma unroll
        for (int mt = 0; mt < 2; ++mt)
            afr[mt] = *(const bf16x8*)&Ws[(mt * 16 + l16) * LDR + quad * 8];
        #pragma unroll
        for (int nt = 0; nt < 2; ++nt)
            bfr[nt] = *(const bf16x8*)&Is[(wave * 32 + nt * 16 + l16) * LDR + quad * 8];
        #pragma unroll
        for (int mt = 0; mt < 2; ++mt)
            #pragma unroll
            for (int nt = 0; nt < 2; ++nt)
                acc[mt][nt] = __builtin_amdgcn_mfma_f32_16x16x32_bf16(
                    afr[mt], bfr[nt], acc[mt][nt], 0, 0, 0);
    }

    #pragma unroll
    for (int mt = 0; mt < 2; ++mt) {
        #pragma unroll
        for (int r = 0; r < 4; ++r) {
            int oc = mt * 16 + quad * 4 + r;
            float scl = scale[oc], shf = shift[oc];
            #pragma unroll
            for (int nt = 0; nt < 2; ++nt) {
                int sg = sb0 + wave * 32 + nt * 16 + l16;
                int n = sg / OHW, s = sg % OHW;
                float v = fmaf(acc[mt][nt][r], scl, shf);
                v = v > 0.f ? v : 0.f;
                out[((size_t)n * 32 + oc) * OHW + s] = (__bf16)v;
            }
        }
    }
}

// ============ generic bf16 MFMA conv body: NOCT 16-oc tiles x 128 spatial ============
template<typename OUTT, int NOCT, int IC, int KS, int RW, int S, int P,
         int IH, int IW, int OH, int OW, int OC, int KTP, int KCH, bool EPI>
DEV void conv_body(
    const __bf16* __restrict__ xo,    // slacked base (>= IW+2 halfs both sides)
    const __bf16* __restrict__ wb,
    const float* __restrict__ scale, const float* __restrict__ shift,
    OUTT* __restrict__ out, __bf16* Is, __bf16* Ws)
{
    constexpr int KITER = KCH / 32;
    constexpr int OHW = OH * OW;
    constexpr int IHW = IH * IW;
    constexpr int LDR = 40;
    constexpr int NROW = 16 / RW;
    constexpr int RU = RW / 2;

    const int tid = threadIdx.x;
    const int sb0 = blockIdx.x * 128;
    const int oc0 = blockIdx.y * (NOCT * 16);

    const int sm = tid & 127;
    const int kpb = tid >> 7;
    int a_n, a_ih0, a_iw0;
    {
        int m = sb0 + sm;
        a_n = m / OHW;
        int rem = m % OHW;
        a_ih0 = (rem / OW) * S - P;
        a_iw0 = (rem % OW) * S - P;
    }
    unsigned ihok = 0;
    #pragma unroll
    for (int t = 0; t < KS; ++t)
        ihok |= (unsigned)(((a_ih0 + t) >= 0) && ((a_ih0 + t) < IH)) << t;
    const bool left = (a_iw0 < 0);
    const __bf16* xp = xo + ((size_t)a_n * IC * IHW + (ptrdiff_t)a_ih0 * IW
                             + (a_iw0 - 1));

    const int w_oc = tid >> 2, w_j = tid & 3;
    const int wave = tid >> 6, lane = tid & 63;
    const int quad = lane >> 4, l16 = lane & 15;

    f32x4 acc[NOCT][2] = {};

    #pragma unroll
    for (int ci = 0; ci < KITER; ++ci) {
        const int k0 = ci * 32;

        union { unsigned u[8]; bf16x8 v[2]; } Pk;
        #pragma unroll
        for (int r = 0; r < NROW; ++r) {
            const int rr = (k0 / RW) + kpb * NROW + r;
            if (rr >= IC * KS) {
                #pragma unroll
                for (int q = 0; q < RU; ++q) Pk.u[r * RU + q] = 0u;
            } else {
                const int ic = rr / KS, kh = rr % KS;
                const unsigned* rp = (const unsigned*)(xp + (ic * IHW + kh * IW));
                unsigned t[RU];
                #pragma unroll
                for (int q = 0; q < RU; ++q) t[q] = rp[q];
                bool rok = (ihok >> kh) & 1u;
                #pragma unroll
                for (int q = 0; q < RU; ++q) t[q] = rok ? t[q] : 0u;
                t[0] = left ? (t[0] & 0x0000FFFFu) : t[0];
                if constexpr (P >= 2) t[1] = left ? 0u : t[1];
                #pragma unroll
                for (int q = 0; q < RU; ++q) Pk.u[r * RU + q] = t[q];
            }
        }
        bf16x8 wv = {};
        if (NOCT == 4 || tid < 128)
            wv = *(const bf16x8*)&wb[(size_t)(oc0 + w_oc) * KTP + k0 + w_j * 8];

        __syncthreads();
        *(bf16x8*)&Is[sm * LDR + kpb * 16]     = Pk.v[0];
        *(bf16x8*)&Is[sm * LDR + kpb * 16 + 8] = Pk.v[1];
        if (NOCT == 4 || tid < 128) *(bf16x8*)&Ws[w_oc * LDR + w_j * 8] = wv;
        __syncthreads();

        bf16x8 afr[NOCT], bfr[2];
        #pragma unroll
        for (int mt = 0; mt < NOCT; ++mt)
            afr[mt] = *(const bf16x8*)&Ws[(mt * 16 + l16) * LDR + quad * 8];
        #pragma unroll
        for (int nt = 0; nt < 2; ++nt)
            bfr[nt] = *(const bf16x8*)&Is[(wave * 32 + nt * 16 + l16) * LDR + quad * 8];
        #pragma unroll
        for (int mt = 0; mt < NOCT; ++mt)
            #pragma unroll
            for (int nt = 0; nt < 2; ++nt)
                acc[mt][nt] = __builtin_amdgcn_mfma_f32_16x16x32_bf16(
                    afr[mt], bfr[nt], acc[mt][nt], 0, 0, 0);
    }

    #pragma unroll
    for (int mt = 0; mt < NOCT; ++mt) {
        #pragma unroll
        for (int r = 0; r < 4; ++r) {
            int oc = oc0 + mt * 16 + quad * 4 + r;
            float scl = EPI ? scale[oc] : 0.f;
            float shf = EPI ? shift[oc] : 0.f;
            #pragma unroll
            for (int nt = 0; nt < 2; ++nt) {
                int sg = sb0 + wave * 32 + nt * 16 + l16;
                int n = sg / OHW, s = sg % OHW;
                float v = acc[mt][nt][r];
                if (EPI) {
                    v = fmaf(v, scl, shf);
                    v = v > 0.f ? v : 0.f;
                }
                out[((size_t)n * OC + oc) * OHW + s] = (OUTT)v;
            }
        }
    }
}

// conv2: 64 oc x 128 spatial (NOCT=4), full K=384 padded
__global__ __launch_bounds__(256, 4) void conv2_kernel(
    const __bf16* __restrict__ xo, const __bf16* __restrict__ wb,
    const float* __restrict__ scale, const float* __restrict__ shift,
    __bf16* __restrict__ out)
{
    __shared__ __attribute__((aligned(16))) __bf16 Is[128 * 40];
    __shared__ __attribute__((aligned(16))) __bf16 Ws[64 * 40];
    conv_body<__bf16, 4, 32, 3, 4, 2, 1, 56, 56, 28, 28, 64, 384, 384, true>(
        xo, wb, scale, shift, out, Is, Ws);
}

// conv3: 32 oc x 128 spatial (NOCT=2), full K=768 padded, bf16 out + epilogue
__global__ __launch_bounds__(256, 6) void conv3_kernel(
    const __bf16* __restrict__ xo, const __bf16* __restrict__ wb,
    const float* __restrict__ scale, const float* __restrict__ shift,
    __bf16* __restrict__ out)
{
    __shared__ __attribute__((aligned(16))) __bf16 Is[128 * 40];
    __shared__ __attribute__((aligned(16))) __bf16 Ws[32 * 40];
    conv_body<__bf16, 2, 64, 3, 4, 2, 1, 28, 28, 14, 14, 128, 768, 768, true>(
        xo, wb, scale, shift, out, Is, Ws);
}

// ============ pool: 7x7 avg over ReLU'd bf16 conv3 output ============
__global__ __launch_bounds__(256) void pool_kernel(
    const __bf16* __restrict__ c3o,      // (N,128,14,14)
    float* __restrict__ f)               // (N,512)
{
    int idx = blockIdx.x * 256 + threadIdx.x;
    int b = idx >> 9, p = idx & 511;
    int c = p >> 2, i = (p >> 1) & 1, j = p & 1;
    size_t base = ((size_t)b * 128 + c) * 196 + (i * 7) * 14 + j * 7;
    float s = 0.f;
    #pragma unroll
    for (int u = 0; u < 7; ++u)
        #pragma unroll
        for (int v = 0; v < 7; ++v)
            s += (float)c3o[base + u * 14 + v];
    f[idx] = s * (1.f / 49.f);
}

// ============ quantum gate helpers ============
DEV void gate_ry(float* re, float* im, int q, float th) {
    float c = cosf(th * 0.5f), s = sinf(th * 0.5f);
    int mask = 8 >> q;
    for (int i = 0; i < 16; ++i) {
        if (i & mask) continue;
        int j = i | mask;
        float r0 = re[i], i0 = im[i], r1 = re[j], i1 = im[j];
        re[i] = c * r0 - s * r1;  im[i] = c * i0 - s * i1;
        re[j] = s * r0 + c * r1;  im[j] = s * i0 + c * i1;
    }
}
DEV void gate_rx(float* re, float* im, int q, float th) {
    float c = cosf(th * 0.5f), s = sinf(th * 0.5f);
    int mask = 8 >> q;
    for (int i = 0; i < 16; ++i) {
        if (i & mask) continue;
        int j = i | mask;
        float r0 = re[i], i0 = im[i], r1 = re[j], i1 = im[j];
        re[i] = c * r0 + s * i1;  im[i] = c * i0 - s * r1;
        re[j] = s * i0 + c * r1;  im[j] = -s * r0 + c * i1;
    }
}
DEV void gate_rz(float* re, float* im, int q, float th) {
    float c = cosf(th * 0.5f), s = sinf(th * 0.5f);
    int mask = 8 >> q;
    for (int i = 0; i < 16; ++i) {
        float sg = (i & mask) ? s : -s;
        float r = re[i], m = im[i];
        re[i] = c * r - sg * m;
        im[i] = c * m + sg * r;
    }
}
DEV void gate_cnot(float* re, float* im, int c, int t) {
    int cm = 8 >> c, tm = 8 >> t;
    for (int i = 0; i < 16; ++i) {
        if ((i & cm) && !(i & tm)) {
            int j = i | tm;
            float r = re[i]; re[i] = re[j]; re[j] = r;
            float m = im[i]; im[i] = im[j]; im[j] = m;
        }
    }
}

// ============ head: linear/tanh -> circuit -> MLP ============
__global__ __launch_bounds__(256) void head_kernel(
    const float* __restrict__ fpool,     // (N,512)
    const float* __restrict__ pre_w, const float* __restrict__ pre_b,
    const float* __restrict__ qw,
    const float* __restrict__ pw1, const float* __restrict__ pb1,
    const float* __restrict__ pw2, const float* __restrict__ pb2,
    float* __restrict__ out)             // (N,5)
{
    __shared__ float f[512];
    __shared__ float ang[4];
    __shared__ float sre[16], simg[16];
    __shared__ float zexp[4];
    __shared__ float h1[64];

    int b = blockIdx.x;
    int t = threadIdx.x;

    for (int p = t; p < 512; p += 256) f[p] = fpool[b * 512 + p];
    __syncthreads();

    int wv = t >> 6, lane = t & 63;
    float partial = 0.f;
    for (int d = lane; d < 512; d += 64)
        partial += f[d] * pre_w[wv * 512 + d];
    #pragma unroll
    for (int off = 32; off > 0; off >>= 1)
        partial += __shfl_down(partial, off, 64);
    if (lane == 0)
        ang[wv] = tanhf(partial + pre_b[wv]) * 3.14159265358979323846f;
    __syncthreads();

    if (t == 0) {
        for (int i = 0; i < 16; ++i) { sre[i] = 0.f; simg[i] = 0.f; }
        sre[0] = 1.f;
        for (int q = 0; q < 4; ++q) gate_ry(sre, simg, q, ang[q]);
        for (int l = 0; l < 2; ++l) {
            for (int q = 0; q < 4; ++q) {
                const float* qq = qw + (l * 4 + q) * 3;
                gate_rx(sre, simg, q, qq[0]);
                gate_ry(sre, simg, q, qq[1]);
                gate_rz(sre, simg, q, qq[2]);
            }
            gate_cnot(sre, simg, 0, 1);
            gate_cnot(sre, simg, 1, 2);
            gate_cnot(sre, simg, 2, 3);
            gate_cnot(sre, simg, 3, 0);
        }
        for (int q = 0; q < 4; ++q) {
            float z = 0.f;
            for (int i = 0; i < 16; ++i) {
                float p2 = sre[i] * sre[i] + simg[i] * simg[i];
                z += (((i >> (3 - q)) & 1) ? -p2 : p2);
            }
            zexp[q] = z;
        }
    }
    __syncthreads();

    if (t < 64) {
        float s = pb1[t];
        #pragma unroll
        for (int k = 0; k < 4; ++k) s += zexp[k] * pw1[t * 4 + k];
        h1[t] = s > 0.f ? s : 0.f;
    }
    __syncthreads();

    if (t < 5) {
        float s = pb2[t];
        for (int k = 0; k < 64; ++k) s += h1[k] * pw2[t * 64 + k];
        out[b * 5 + t] = s;
    }
}

extern "C" void kernel_launch(void* const* d_in, const int* in_sizes, int n_in,
                              void* d_out, int out_size, void* d_ws, size_t ws_size,
                              hipStream_t stream) {
    const float* x    = (const float*)d_in[0];
    const float* c1w  = (const float*)d_in[1];
    const float* c1b  = (const float*)d_in[2];
    const float* bn1g = (const float*)d_in[3];
    const float* bn1b = (const float*)d_in[4];
    const float* bn1m = (const float*)d_in[5];
    const float* bn1v = (const float*)d_in[6];
    const float* c2w  = (const float*)d_in[7];
    const float* c2b  = (const float*)d_in[8];
    const float* bn2g = (const float*)d_in[9];
    const float* bn2b = (const float*)d_in[10];
    const float* bn2m = (const float*)d_in[11];
    const float* bn2v = (const float*)d_in[12];
    const float* c3w  = (const float*)d_in[13];
    const float* c3bi = (const float*)d_in[14];
    const float* bn3g = (const float*)d_in[15];
    const float* bn3b = (const float*)d_in[16];
    const float* bn3m = (const float*)d_in[17];
    const float* bn3v = (const float*)d_in[18];
    const float* prw  = (const float*)d_in[19];
    const float* prb  = (const float*)d_in[20];
    const float* qw   = (const float*)d_in[21];
    const float* pw1  = (const float*)d_in[22];
    const float* pb1  = (const float*)d_in[23];
    const float* pw2  = (const float*)d_in[24];
    const float* pb2  = (const float*)d_in[25];

    const int N = in_sizes[0] / (3 * 224 * 224);   // 128
    const size_t NC1 = (size_t)N * 32 * 56 * 56;   // 12,845,056
    const size_t NC2 = (size_t)N * 64 * 28 * 28;   //  6,422,528
    const size_t NC3 = (size_t)N * 128 * 14 * 14;  //  3,211,264

    // ---- workspace layout (halfs; all bases multiples of 8 => 16B aligned) ----
    __bf16* ws_h = (__bf16*)d_ws;
    __bf16* c1o = ws_h + 64;                       // slack 64 both sides
    __bf16* c2o = ws_h + 64 + NC1 + 64 + 64;
    __bf16* c3o = ws_h + 64 + NC1 + 64 + 64 + NC2 + 64;
    __bf16* wb1 = c3o + NC3;                       // 32*192
    __bf16* wb2 = wb1 + 32 * 192;                  // 64*384
    __bf16* wb3 = wb2 + 64 * 384;                  // 128*768
    float* sc1 = (float*)(wb3 + 128 * 768);
    float* sh1 = sc1 + 32;
    float* sc2 = sh1 + 32;  float* sh2 = sc2 + 64;
    float* sc3 = sh2 + 64;  float* sh3 = sc3 + 128;
    float* fpool = sh3 + 128;                      // N*512 floats

    prep_weights<<<192, 256, 0, stream>>>(
        c1w, c1b, bn1g, bn1b, bn1m, bn1v,
        c2w, c2b, bn2g, bn2b, bn2m, bn2v,
        c3w, c3bi, bn3g, bn3b, bn3m, bn3v,
        wb1, wb2, wb3, sc1, sh1, sc2, sh2, sc3, sh3);

    // conv1: fp32 x directly, 3136 blocks
    conv1_kernel<<<dim3(401408 / 128, 1), 256, 0, stream>>>(x, wb1, sc1, sh1, c1o);
    // conv2: 64-oc blocks, 784 blocks
    conv2_kernel<<<dim3(100352 / 128, 1), 256, 0, stream>>>(c1o, wb2, sc2, sh2, c2o);
    // conv3: full-K, 32-oc blocks, (196,4) = 784 blocks, bf16 out
    conv3_kernel<<<dim3(25088 / 128, 4), 256, 0, stream>>>(c2o, wb3, sc3, sh3, c3o);

    pool_kernel<<<(N * 512) / 256, 256, 0, stream>>>(c3o, fpool);
    head_kernel<<<N, 256, 0, stream>>>(fpool, prw, prb, qw,
                                       pw1, pb1, pw2, pb2, (float*)d_out);
}